// Round 15
// baseline (130.670 us; speedup 1.0000x reference)
//
#include <hip/hip_runtime.h>

typedef __attribute__((ext_vector_type(8))) _Float16 f16x8;
typedef __attribute__((ext_vector_type(4))) float f32x4;
typedef __attribute__((ext_vector_type(16))) float f32x16;
typedef __attribute__((ext_vector_type(2))) int int2v;
typedef __attribute__((ext_vector_type(4))) int int4v;

#define DEVI __device__ __forceinline__

DEVI unsigned short f2h(float f){
  _Float16 h = (_Float16)f;
  return __builtin_bit_cast(unsigned short, h);
}
DEVI float fexp2(float x){ return __builtin_amdgcn_exp2f(x); }  // raw v_exp_f32

// ---------------- kernel 1: weights fp32 -> fp16 ----------------
__global__ __launch_bounds__(256) void k_wconv(
    const float* __restrict__ tw, const float* __restrict__ pw,
    const float* __restrict__ gw, const float* __restrict__ ow,
    unsigned short* __restrict__ dst){
  int i = blockIdx.x*256 + threadIdx.x;
  int a = i>>15, off = i & 32767;
  const float* s = (a==0)?tw:(a==1)?pw:(a==2)?gw:ow;
  dst[i] = f2h(s[off]);
}

// ---------------- kernel 2: fused projections (XCD-pinned) ------
__global__ __launch_bounds__(256) void k_proj(
    const float* __restrict__ x,
    const unsigned short* __restrict__ Wq, const unsigned short* __restrict__ Wk,
    const unsigned short* __restrict__ Wg,
    const float* __restrict__ tb, const float* __restrict__ pb,
    const float* __restrict__ gb,
    unsigned short* __restrict__ Q, unsigned short* __restrict__ Km,
    unsigned short* __restrict__ VT)
{
  __shared__ __align__(16) unsigned short xT[64*264];
  const int tid = threadIdx.x;
  const int w = tid>>6, l = tid&63, l15 = l&15, lhi = l>>4;
  const int id = blockIdx.x;
  const int b = id & 7, n0 = (id>>3)*64;

  const float* xb = x + (size_t)b*256*4096 + n0;
  #pragma unroll 4
  for (int i=0;i<32;++i){
    int c = 64*w + 2*i;
    float v0 = xb[(size_t)c*4096 + l];
    float v1 = xb[(size_t)(c+1)*4096 + l];
    unsigned int pk = (unsigned int)f2h(v0) | ((unsigned int)f2h(v1)<<16);
    *(unsigned int*)&xT[l*264 + c] = pk;
  }
  __syncthreads();

  for (int mat=0; mat<2; ++mat){
    const unsigned short* Wm = mat ? Wk : Wq;
    const float* bias = mat ? pb : tb;
    unsigned short* Out = mat ? Km : Q;
    const float scl = mat ? 1.0f : 1.44269504f;   // fold log2e into Q
    for (int pbk=0; pbk<4; ++pbk){
      f16x8 aF[8];
      #pragma unroll
      for (int ks=0;ks<8;++ks)
        aF[ks] = *(const f16x8*)&xT[(16*pbk + l15)*264 + lhi*8 + 32*ks];
      #pragma unroll
      for (int kb2=0; kb2<2; ++kb2){
        int kb = 2*w + kb2;
        f32x4 acc = {0.f,0.f,0.f,0.f};
        #pragma unroll
        for (int ks=0;ks<8;++ks){
          f16x8 bF = *(const f16x8*)&Wm[(size_t)(16*kb + l15)*256 + lhi*8 + 32*ks];
          acc = __builtin_amdgcn_mfma_f32_16x16x32_f16(aF[ks], bF, acc, 0,0,0);
        }
        float bv = bias[16*kb + l15];
        #pragma unroll
        for (int r=0;r<4;++r){
          int pix = 16*pbk + lhi*4 + r;
          Out[((size_t)b*4096 + n0 + pix)*128 + 16*kb + l15] = f2h((acc[r] + bv)*scl);
        }
      }
    }
  }

  for (int nb=0; nb<4; ++nb){
    f16x8 bF[8];
    #pragma unroll
    for (int ks=0;ks<8;++ks)
      bF[ks] = *(const f16x8*)&xT[(16*nb + l15)*264 + lhi*8 + 32*ks];
    #pragma unroll
    for (int mb2=0; mb2<2; ++mb2){
      int mb = 2*w + mb2;
      f32x4 acc = {0.f,0.f,0.f,0.f};
      #pragma unroll
      for (int ks=0;ks<8;++ks){
        f16x8 aF = *(const f16x8*)&Wg[(size_t)(16*mb + l15)*256 + lhi*8 + 32*ks];
        acc = __builtin_amdgcn_mfma_f32_16x16x32_f16(aF, bF[ks], acc, 0,0,0);
      }
      #pragma unroll
      for (int r=0;r<4;++r){
        int k = 16*mb + lhi*4 + r;
        VT[((size_t)b*128 + k)*4096 + n0 + 16*nb + l15] = f2h(acc[r] + gb[k]);
      }
    }
  }
}

// ---------------- staging: global -> LDS (linear dest, pre-swizzled src) ---
// f(row) = ((row&7) ^ ((row>>2)&4)) << 4  (matches read-side swz)
DEVI void stage_K(const char* Kg, int nt, char* Kd, int w, int l){
  #pragma unroll
  for (int c=0;c<4;++c){
    int base = (4*w + c)*1024;
    int lin  = base + l*16;
    int row = lin>>8, colb = lin&255;        // [64][256B]
    int f = ((row&7) ^ ((row>>2)&4)) << 4;
    const char* g = Kg + (size_t)(nt*64 + row)*256 + (colb ^ f);
    __builtin_amdgcn_global_load_lds((const __attribute__((address_space(1))) void*)g,
        (__attribute__((address_space(3))) void*)(Kd + base), 16, 0, 0);
  }
}
DEVI void stage_V(const char* Vg, int nt, char* Vd, int w, int l){
  #pragma unroll
  for (int c=0;c<4;++c){
    int base = (4*w + c)*1024;
    int lin  = base + l*16;
    int row = lin>>7, colb = lin&127;        // [128][128B]
    int f = ((row&7) ^ ((row>>2)&4)) << 4;
    const char* g = Vg + (size_t)row*8192 + (size_t)nt*128 + (colb ^ f);
    __builtin_amdgcn_global_load_lds((const __attribute__((address_space(1))) void*)g,
        (__attribute__((address_space(3))) void*)(Vd + base), 16, 0, 0);
  }
}

// ---------------- kernel 3: flash attention, cross-iteration pipelined -----
// body(t): stage(t+1); QK^T(t) -> stCur; softmax+PV(tile t-1, stPrev); barrier.
// T5: setprio(1) around both MFMA clusters — waves on a SIMD sit in skewed
// phases (QK^T vs softmax); priority keeps the matrix pipe fed.
// K double-buffered, V TRIPLE-buffered. LDS 80KB -> 2 blocks/CU.
// 1-D grid 512, b = id&7 (XCD-pinned), qt = (id>>3)&31, h = id>>8.
__global__ __launch_bounds__(256, 2) void k_attn(
    const unsigned short* __restrict__ Q, const unsigned short* __restrict__ Km,
    const unsigned short* __restrict__ VT,
    unsigned short* __restrict__ On,     // [2][8][4096][128] f16, normalized
    float* __restrict__ Mp, float* __restrict__ Lp)  // [2][8][4096], m in log2
{
  __shared__ __align__(16) unsigned short K_lds[2][64*128];
  __shared__ __align__(16) unsigned short V_lds[3][128*64];
  const int tid = threadIdx.x;
  const int w = tid>>6, l = tid&63;
  const int q32 = l & 31, hi = l >> 5;
  const int id = blockIdx.x;
  const int b = id & 7;                       // XCD-pinned batch
  const int qt = (id >> 3) & 31, h = id >> 8;
  const int n0 = qt*128, wq0 = w*32, nt0 = h*32;
  const int swz = ((q32&7) ^ ((q32>>2)&4)) << 4;

  const unsigned short* Qrow = Q + ((size_t)b*4096 + n0 + wq0 + q32)*128;
  f16x8 qf[8];
  #pragma unroll
  for (int ks=0; ks<8; ++ks)
    qf[ks] = *(const f16x8*)&Qrow[ks*16 + hi*8];

  const char* Kg = (const char*)(Km + (size_t)b*4096*128);
  const char* Vg = (const char*)(VT + (size_t)b*128*4096);

  float m_run = -3.0e38f, l_loc = 0.f;   // l accumulated per-lane; merged at end
  f32x16 ob[4] = {};
  f32x16 stA[2], stB[2];

  auto QKT = [&](const char* Kc, f32x16* st){
    __builtin_amdgcn_s_setprio(1);
    #pragma unroll
    for (int mt=0; mt<2; ++mt){
      f32x16 a = {};
      int rb = (32*mt + q32)*256;
      #pragma unroll
      for (int ks=0; ks<8; ++ks){
        f16x8 kf = *(const f16x8*)(Kc + rb + ((16*hi + 32*ks) ^ swz));
        a = __builtin_amdgcn_mfma_f32_32x32x16_f16(kf, qf[ks], a, 0,0,0);
      }
      st[mt] = a;
    }
    __builtin_amdgcn_s_setprio(0);
  };

  auto SMPV = [&](f32x16* st, const char* Vc){
    float mx;
    {
      float t0 = fmaxf(fmaxf(st[0][0], st[0][1]), fmaxf(st[0][2], st[0][3]));
      float t1 = fmaxf(fmaxf(st[0][4], st[0][5]), fmaxf(st[0][6], st[0][7]));
      float t2 = fmaxf(fmaxf(st[0][8], st[0][9]), fmaxf(st[0][10], st[0][11]));
      float t3 = fmaxf(fmaxf(st[0][12], st[0][13]), fmaxf(st[0][14], st[0][15]));
      float t4 = fmaxf(fmaxf(st[1][0], st[1][1]), fmaxf(st[1][2], st[1][3]));
      float t5 = fmaxf(fmaxf(st[1][4], st[1][5]), fmaxf(st[1][6], st[1][7]));
      float t6 = fmaxf(fmaxf(st[1][8], st[1][9]), fmaxf(st[1][10], st[1][11]));
      float t7 = fmaxf(fmaxf(st[1][12], st[1][13]), fmaxf(st[1][14], st[1][15]));
      mx = fmaxf(fmaxf(fmaxf(t0,t1), fmaxf(t2,t3)), fmaxf(fmaxf(t4,t5), fmaxf(t6,t7)));
    }
    mx = fmaxf(mx, __shfl_xor(mx, 32));
    if (!__all(mx <= m_run + 11.5416f)){
      float mn = fmaxf(m_run, mx);
      float sc = fexp2(m_run - mn);
      l_loc *= sc;
      #pragma unroll
      for (int db=0; db<4; ++db) ob[db] *= sc;
      m_run = mn;
    }
    float ps = 0.f;
    #pragma unroll
    for (int mt=0; mt<2; ++mt)
      #pragma unroll
      for (int r=0; r<16; ++r){
        float p = fexp2(st[mt][r] - m_run);
        st[mt][r] = p; ps += p;
      }
    l_loc += ps;
    __builtin_amdgcn_s_setprio(1);
    #pragma unroll
    for (int ks=0; ks<4; ++ks){
      const int mt = ks>>1, u = ks&1;
      int X0 = __builtin_bit_cast(int, __builtin_amdgcn_cvt_pkrtz(st[mt][8*u+0], st[mt][8*u+1]));
      int X1 = __builtin_bit_cast(int, __builtin_amdgcn_cvt_pkrtz(st[mt][8*u+2], st[mt][8*u+3]));
      int Y0 = __builtin_bit_cast(int, __builtin_amdgcn_cvt_pkrtz(st[mt][8*u+4], st[mt][8*u+5]));
      int Y1 = __builtin_bit_cast(int, __builtin_amdgcn_cvt_pkrtz(st[mt][8*u+6], st[mt][8*u+7]));
      int2v rA = __builtin_amdgcn_permlane32_swap(X0, Y0, false, false);
      int2v rB = __builtin_amdgcn_permlane32_swap(X1, Y1, false, false);
      int4v wv = {rA[0], rB[0], rA[1], rB[1]};
      f16x8 pf = __builtin_bit_cast(f16x8, wv);
      #pragma unroll
      for (int db=0; db<4; ++db){
        f16x8 vf = *(const f16x8*)(Vc + (32*db + q32)*128 + ((16*hi + 32*ks) ^ swz));
        ob[db] = __builtin_amdgcn_mfma_f32_32x32x16_f16(vf, pf, ob[db], 0,0,0);
      }
    }
    __builtin_amdgcn_s_setprio(0);
  };

  // rotating V buffer pointers: before body(t), vprev=V[(t-1)%3], vcur=V[t%3],
  // vnext=V[(t+1)%3]
  char* vprev = (char*)V_lds[2];
  char* vcur  = (char*)V_lds[0];
  char* vnext = (char*)V_lds[1];

  // prologue: stage tile 0
  stage_K(Kg, nt0, (char*)K_lds[0], w, l);
  stage_V(Vg, nt0, vcur, w, l);
  __syncthreads();

  // body 0: stage(1); QK^T(0)->stA; (no softmax/PV); barrier
  stage_K(Kg, nt0+1, (char*)K_lds[1], w, l);
  stage_V(Vg, nt0+1, vnext, w, l);
  QKT((const char*)K_lds[0], stA);
  __syncthreads();
  { char* t=vprev; vprev=vcur; vcur=vnext; vnext=t; }

  #pragma unroll 1
  for (int tt=0; tt<15; ++tt){
    const int t1 = 2*tt+1;
    // body t1 (odd): reads K[1], stages K[0]
    stage_K(Kg, nt0+t1+1, (char*)K_lds[0], w, l);
    stage_V(Vg, nt0+t1+1, vnext, w, l);
    QKT((const char*)K_lds[1], stB);
    SMPV(stA, vprev);
    __syncthreads();
    { char* t=vprev; vprev=vcur; vcur=vnext; vnext=t; }
    // body t1+1 (even): reads K[0], stages K[1]
    stage_K(Kg, nt0+t1+2, (char*)K_lds[1], w, l);
    stage_V(Vg, nt0+t1+2, vnext, w, l);
    QKT((const char*)K_lds[0], stA);
    SMPV(stB, vprev);
    __syncthreads();
    { char* t=vprev; vprev=vcur; vcur=vnext; vnext=t; }
  }
  // body 31 (odd, no staging): QK^T(31)->stB; softmax+PV(30)
  QKT((const char*)K_lds[1], stB);
  SMPV(stA, vprev);
  { char* t=vprev; vprev=vcur; vcur=vnext; vnext=t; }
  // epilogue: softmax+PV(31)
  SMPV(stB, vprev);

  // ---- epilogue: O^T[d regs][q=lane&31] -> normalized f16 partials ----
  float l_run = l_loc + __shfl_xor(l_loc, 32);
  float invl = 1.0f / l_run;
  unsigned short* Orow = On + (((size_t)(h*8 + b)*4096) + n0 + wq0 + q32)*128;
  #pragma unroll
  for (int db=0; db<4; ++db)
    #pragma unroll
    for (int g=0; g<4; ++g){
      int2v pk2;
      pk2[0] = __builtin_bit_cast(int, __builtin_amdgcn_cvt_pkrtz(ob[db][4*g+0]*invl, ob[db][4*g+1]*invl));
      pk2[1] = __builtin_bit_cast(int, __builtin_amdgcn_cvt_pkrtz(ob[db][4*g+2]*invl, ob[db][4*g+3]*invl));
      *(int2v*)&Orow[32*db + 8*g + 4*hi] = pk2;
    }
  if (l < 32){
    size_t idx = (size_t)(h*8+b)*4096 + n0 + wq0 + l;
    Mp[idx] = m_run;
    Lp[idx] = l_run;
  }
}

// ---------------- kernel 4: merge halves + out-proj + residual ----
// 1-D grid 1024, b = id&7 (XCD-pinned), 32-row tiles.
__global__ __launch_bounds__(256) void k_merge(
    const unsigned short* __restrict__ On, const float* __restrict__ Mp,
    const float* __restrict__ Lp,
    const unsigned short* __restrict__ Wo, const float* __restrict__ out_b,
    const float* __restrict__ x, float* __restrict__ out)
{
  __shared__ __align__(16) unsigned short y_lds[32*136];
  const int tid = threadIdx.x;
  const int id = blockIdx.x;
  const int b = id & 7, n0 = (id>>3)*32;

  { // phase 1: y = w0*On0 + w1*On1 -> y_lds [n][k] f16
    int row = tid>>3, dq = (tid&7)*16;
    size_t i0 = (size_t)b*4096 + n0 + row;
    size_t i1 = (size_t)(8+b)*4096 + n0 + row;
    float m0 = Mp[i0], m1 = Mp[i1], l0 = Lp[i0], l1 = Lp[i1];
    float M = fmaxf(m0, m1);
    float a0 = fexp2(m0 - M)*l0, a1 = fexp2(m1 - M)*l1;
    float inv = 1.0f/(a0 + a1);
    float w0 = a0*inv, w1 = a1*inv;
    const unsigned short* p0 = On + i0*128 + dq;
    const unsigned short* p1 = On + i1*128 + dq;
    #pragma unroll
    for (int i=0;i<2;++i){
      f16x8 o0 = *(const f16x8*)&p0[8*i];
      f16x8 o1 = *(const f16x8*)&p1[8*i];
      int4v pk;
      #pragma unroll
      for (int j=0;j<4;++j){
        float ya = w0*(float)o0[2*j]   + w1*(float)o1[2*j];
        float yb = w0*(float)o0[2*j+1] + w1*(float)o1[2*j+1];
        pk[j] = __builtin_bit_cast(int, __builtin_amdgcn_cvt_pkrtz(ya, yb));
      }
      *(int4v*)&y_lds[row*136 + dq + 8*i] = pk;
    }
  }
  __syncthreads();

  // phase 2: out = y . Wo^T + out_b + x
  const int w = tid>>6, l = tid&63, l15 = l&15, lhi = l>>4;
  const float* xb = x + (size_t)b*256*4096;
  const f32x4 zero4 = {0.f,0.f,0.f,0.f};
  for (int cb=0; cb<4; ++cb){
    int c0 = 64*w + 16*cb;
    f16x8 aW[4];
    #pragma unroll
    for (int ks=0;ks<4;++ks)
      aW[ks] = *(const f16x8*)&Wo[(size_t)(c0 + l15)*128 + lhi*8 + 32*ks];
    float obv[4];
    #pragma unroll
    for (int r=0;r<4;++r) obv[r] = out_b[c0 + lhi*4 + r];
    #pragma unroll
    for (int nb=0;nb<2;++nb){
      f32x4 acc = zero4;
      #pragma unroll
      for (int ks=0;ks<4;++ks){
        f16x8 yF = *(const f16x8*)&y_lds[(16*nb + l15)*136 + lhi*8 + 32*ks];
        acc = __builtin_amdgcn_mfma_f32_16x16x32_f16(aW[ks], yF, acc, 0,0,0);
      }
      #pragma unroll
      for (int r=0;r<4;++r){
        int c = c0 + lhi*4 + r;
        size_t oi = (size_t)c*4096 + n0 + 16*nb + l15;
        out[(size_t)b*256*4096 + oi] = acc[r] + obv[r] + xb[oi];
      }
    }
  }
}

extern "C" void kernel_launch(void* const* d_in, const int* in_sizes, int n_in,
                              void* d_out, int out_size, void* d_ws, size_t ws_size,
                              hipStream_t stream) {
  (void)in_sizes; (void)n_in; (void)out_size; (void)ws_size;
  const float* x  = (const float*)d_in[0];
  const float* tw = (const float*)d_in[1];
  const float* tb = (const float*)d_in[2];
  const float* pw = (const float*)d_in[3];
  const float* pb = (const float*)d_in[4];
  const float* gw = (const float*)d_in[5];
  const float* gb = (const float*)d_in[6];
  const float* ow = (const float*)d_in[7];
  const float* ob = (const float*)d_in[8];
  float* out = (float*)d_out;

  unsigned short* ws = (unsigned short*)d_ws;
  unsigned short* Wq = ws;                       // 4 x 32768 f16 weights
  unsigned short* Wk = ws + 32768;
  unsigned short* Wg = ws + 65536;
  unsigned short* Wo = ws + 98304;
  unsigned short* Q  = ws + 131072;              // 8*4096*128 f16 each
  unsigned short* Km = Q  + 4194304;
  unsigned short* VT = Km + 4194304;
  unsigned short* On = VT + 4194304;             // 2*8*4096*128 f16
  float* Mp = (float*)(On + 8388608);            // 2*8*4096 f32 (log2 units)
  float* Lp = Mp + 65536;

  hipLaunchKernelGGL(k_wconv, dim3(512), dim3(256), 0, stream, tw, pw, gw, ow, ws);
  hipLaunchKernelGGL(k_proj,  dim3(512), dim3(256), 0, stream,
                     x, Wq, Wk, Wg, tb, pb, gb, Q, Km, VT);
  hipLaunchKernelGGL(k_attn,  dim3(512), dim3(256), 0, stream,
                     Q, Km, VT, On, Mp, Lp);
  hipLaunchKernelGGL(k_merge, dim3(1024), dim3(256), 0, stream,
                     On, Mp, Lp, Wo, ob, x, out);
}

// Round 16
// 128.253 us; speedup vs baseline: 1.0188x; 1.0188x over previous
//
#include <hip/hip_runtime.h>

typedef __attribute__((ext_vector_type(8))) _Float16 f16x8;
typedef __attribute__((ext_vector_type(4))) float f32x4;
typedef __attribute__((ext_vector_type(16))) float f32x16;
typedef __attribute__((ext_vector_type(2))) int int2v;
typedef __attribute__((ext_vector_type(4))) int int4v;

#define DEVI __device__ __forceinline__

DEVI unsigned short f2h(float f){
  _Float16 h = (_Float16)f;
  return __builtin_bit_cast(unsigned short, h);
}
DEVI float fexp2(float x){ return __builtin_amdgcn_exp2f(x); }  // raw v_exp_f32

// ---------------- kernel 1: weights fp32 -> fp16 ----------------
__global__ __launch_bounds__(256) void k_wconv(
    const float* __restrict__ tw, const float* __restrict__ pw,
    const float* __restrict__ gw, const float* __restrict__ ow,
    unsigned short* __restrict__ dst){
  int i = blockIdx.x*256 + threadIdx.x;
  int a = i>>15, off = i & 32767;
  const float* s = (a==0)?tw:(a==1)?pw:(a==2)?gw:ow;
  dst[i] = f2h(s[off]);
}

// ---------------- kernel 2: fused projections (XCD-pinned) ------
__global__ __launch_bounds__(256) void k_proj(
    const float* __restrict__ x,
    const unsigned short* __restrict__ Wq, const unsigned short* __restrict__ Wk,
    const unsigned short* __restrict__ Wg,
    const float* __restrict__ tb, const float* __restrict__ pb,
    const float* __restrict__ gb,
    unsigned short* __restrict__ Q, unsigned short* __restrict__ Km,
    unsigned short* __restrict__ VT)
{
  __shared__ __align__(16) unsigned short xT[64*264];
  const int tid = threadIdx.x;
  const int w = tid>>6, l = tid&63, l15 = l&15, lhi = l>>4;
  const int id = blockIdx.x;
  const int b = id & 7, n0 = (id>>3)*64;

  const float* xb = x + (size_t)b*256*4096 + n0;
  #pragma unroll 4
  for (int i=0;i<32;++i){
    int c = 64*w + 2*i;
    float v0 = xb[(size_t)c*4096 + l];
    float v1 = xb[(size_t)(c+1)*4096 + l];
    unsigned int pk = (unsigned int)f2h(v0) | ((unsigned int)f2h(v1)<<16);
    *(unsigned int*)&xT[l*264 + c] = pk;
  }
  __syncthreads();

  for (int mat=0; mat<2; ++mat){
    const unsigned short* Wm = mat ? Wk : Wq;
    const float* bias = mat ? pb : tb;
    unsigned short* Out = mat ? Km : Q;
    const float scl = mat ? 1.0f : 1.44269504f;   // fold log2e into Q
    for (int pbk=0; pbk<4; ++pbk){
      f16x8 aF[8];
      #pragma unroll
      for (int ks=0;ks<8;++ks)
        aF[ks] = *(const f16x8*)&xT[(16*pbk + l15)*264 + lhi*8 + 32*ks];
      #pragma unroll
      for (int kb2=0; kb2<2; ++kb2){
        int kb = 2*w + kb2;
        f32x4 acc = {0.f,0.f,0.f,0.f};
        #pragma unroll
        for (int ks=0;ks<8;++ks){
          f16x8 bF = *(const f16x8*)&Wm[(size_t)(16*kb + l15)*256 + lhi*8 + 32*ks];
          acc = __builtin_amdgcn_mfma_f32_16x16x32_f16(aF[ks], bF, acc, 0,0,0);
        }
        float bv = bias[16*kb + l15];
        #pragma unroll
        for (int r=0;r<4;++r){
          int pix = 16*pbk + lhi*4 + r;
          Out[((size_t)b*4096 + n0 + pix)*128 + 16*kb + l15] = f2h((acc[r] + bv)*scl);
        }
      }
    }
  }

  for (int nb=0; nb<4; ++nb){
    f16x8 bF[8];
    #pragma unroll
    for (int ks=0;ks<8;++ks)
      bF[ks] = *(const f16x8*)&xT[(16*nb + l15)*264 + lhi*8 + 32*ks];
    #pragma unroll
    for (int mb2=0; mb2<2; ++mb2){
      int mb = 2*w + mb2;
      f32x4 acc = {0.f,0.f,0.f,0.f};
      #pragma unroll
      for (int ks=0;ks<8;++ks){
        f16x8 aF = *(const f16x8*)&Wg[(size_t)(16*mb + l15)*256 + lhi*8 + 32*ks];
        acc = __builtin_amdgcn_mfma_f32_16x16x32_f16(aF, bF[ks], acc, 0,0,0);
      }
      #pragma unroll
      for (int r=0;r<4;++r){
        int k = 16*mb + lhi*4 + r;
        VT[((size_t)b*128 + k)*4096 + n0 + 16*nb + l15] = f2h(acc[r] + gb[k]);
      }
    }
  }
}

// ---------------- staging: global -> LDS (linear dest, pre-swizzled src) ---
// K: fK(row) = (row&15)<<4  -> 16 slots, 2 lanes/slot on read (2-way, free)
// V: fV(row) = ((row&7)^((row>>2)&4))<<4 (8 slots; 4-way inherent at 128B rows)
DEVI void stage_K(const char* Kg, int nt, char* Kd, int w, int l){
  #pragma unroll
  for (int c=0;c<4;++c){
    int base = (4*w + c)*1024;
    int lin  = base + l*16;
    int row = lin>>8, colb = lin&255;        // [64][256B]
    int f = (row&15)<<4;
    const char* g = Kg + (size_t)(nt*64 + row)*256 + (colb ^ f);
    __builtin_amdgcn_global_load_lds((const __attribute__((address_space(1))) void*)g,
        (__attribute__((address_space(3))) void*)(Kd + base), 16, 0, 0);
  }
}
DEVI void stage_V(const char* Vg, int nt, char* Vd, int w, int l){
  #pragma unroll
  for (int c=0;c<4;++c){
    int base = (4*w + c)*1024;
    int lin  = base + l*16;
    int row = lin>>7, colb = lin&127;        // [128][128B]
    int f = ((row&7) ^ ((row>>2)&4)) << 4;
    const char* g = Vg + (size_t)row*8192 + (size_t)nt*128 + (colb ^ f);
    __builtin_amdgcn_global_load_lds((const __attribute__((address_space(1))) void*)g,
        (__attribute__((address_space(3))) void*)(Vd + base), 16, 0, 0);
  }
}

// ---------------- kernel 3: flash attention, cross-iteration pipelined -----
// body(t): stage(t+1); QK^T(t) -> stCur; softmax+PV(tile t-1, stPrev); barrier.
// K double-buffered, V TRIPLE-buffered. LDS 80KB -> 2 blocks/CU.
// 1-D grid 512, b = id&7 (XCD-pinned), qt = (id>>3)&31, h = id>>8.
__global__ __launch_bounds__(256, 2) void k_attn(
    const unsigned short* __restrict__ Q, const unsigned short* __restrict__ Km,
    const unsigned short* __restrict__ VT,
    unsigned short* __restrict__ On,     // [2][8][4096][128] f16, normalized
    float* __restrict__ Mp, float* __restrict__ Lp)  // [2][8][4096], m in log2
{
  __shared__ __align__(16) unsigned short K_lds[2][64*128];
  __shared__ __align__(16) unsigned short V_lds[3][128*64];
  const int tid = threadIdx.x;
  const int w = tid>>6, l = tid&63;
  const int q32 = l & 31, hi = l >> 5;
  const int id = blockIdx.x;
  const int b = id & 7;                       // XCD-pinned batch
  const int qt = (id >> 3) & 31, h = id >> 8;
  const int n0 = qt*128, wq0 = w*32, nt0 = h*32;
  const int swzK = (q32&15) << 4;                       // 16-slot K swizzle
  const int swzV = ((q32&7) ^ ((q32>>2)&4)) << 4;       // V swizzle (as staged)

  const unsigned short* Qrow = Q + ((size_t)b*4096 + n0 + wq0 + q32)*128;
  f16x8 qf[8];
  #pragma unroll
  for (int ks=0; ks<8; ++ks)
    qf[ks] = *(const f16x8*)&Qrow[ks*16 + hi*8];

  const char* Kg = (const char*)(Km + (size_t)b*4096*128);
  const char* Vg = (const char*)(VT + (size_t)b*128*4096);

  float m_run = -3.0e38f, l_loc = 0.f;   // l accumulated per-lane; merged at end
  f32x16 ob[4] = {};
  f32x16 stA[2], stB[2];

  auto QKT = [&](const char* Kc, f32x16* st){
    #pragma unroll
    for (int mt=0; mt<2; ++mt){
      f32x16 a = {};
      int rb = (32*mt + q32)*256;
      #pragma unroll
      for (int ks=0; ks<8; ++ks){
        f16x8 kf = *(const f16x8*)(Kc + rb + ((16*hi + 32*ks) ^ swzK));
        a = __builtin_amdgcn_mfma_f32_32x32x16_f16(kf, qf[ks], a, 0,0,0);
      }
      st[mt] = a;
    }
  };

  auto SMPV = [&](f32x16* st, const char* Vc){
    float mx;
    {
      float t0 = fmaxf(fmaxf(st[0][0], st[0][1]), fmaxf(st[0][2], st[0][3]));
      float t1 = fmaxf(fmaxf(st[0][4], st[0][5]), fmaxf(st[0][6], st[0][7]));
      float t2 = fmaxf(fmaxf(st[0][8], st[0][9]), fmaxf(st[0][10], st[0][11]));
      float t3 = fmaxf(fmaxf(st[0][12], st[0][13]), fmaxf(st[0][14], st[0][15]));
      float t4 = fmaxf(fmaxf(st[1][0], st[1][1]), fmaxf(st[1][2], st[1][3]));
      float t5 = fmaxf(fmaxf(st[1][4], st[1][5]), fmaxf(st[1][6], st[1][7]));
      float t6 = fmaxf(fmaxf(st[1][8], st[1][9]), fmaxf(st[1][10], st[1][11]));
      float t7 = fmaxf(fmaxf(st[1][12], st[1][13]), fmaxf(st[1][14], st[1][15]));
      mx = fmaxf(fmaxf(fmaxf(t0,t1), fmaxf(t2,t3)), fmaxf(fmaxf(t4,t5), fmaxf(t6,t7)));
    }
    mx = fmaxf(mx, __shfl_xor(mx, 32));
    if (!__all(mx <= m_run + 11.5416f)){
      float mn = fmaxf(m_run, mx);
      float sc = fexp2(m_run - mn);
      l_loc *= sc;
      #pragma unroll
      for (int db=0; db<4; ++db) ob[db] *= sc;
      m_run = mn;
    }
    float ps = 0.f;
    #pragma unroll
    for (int mt=0; mt<2; ++mt)
      #pragma unroll
      for (int r=0; r<16; ++r){
        float p = fexp2(st[mt][r] - m_run);
        st[mt][r] = p; ps += p;
      }
    l_loc += ps;
    #pragma unroll
    for (int ks=0; ks<4; ++ks){
      const int mt = ks>>1, u = ks&1;
      int X0 = __builtin_bit_cast(int, __builtin_amdgcn_cvt_pkrtz(st[mt][8*u+0], st[mt][8*u+1]));
      int X1 = __builtin_bit_cast(int, __builtin_amdgcn_cvt_pkrtz(st[mt][8*u+2], st[mt][8*u+3]));
      int Y0 = __builtin_bit_cast(int, __builtin_amdgcn_cvt_pkrtz(st[mt][8*u+4], st[mt][8*u+5]));
      int Y1 = __builtin_bit_cast(int, __builtin_amdgcn_cvt_pkrtz(st[mt][8*u+6], st[mt][8*u+7]));
      int2v rA = __builtin_amdgcn_permlane32_swap(X0, Y0, false, false);
      int2v rB = __builtin_amdgcn_permlane32_swap(X1, Y1, false, false);
      int4v wv = {rA[0], rB[0], rA[1], rB[1]};
      f16x8 pf = __builtin_bit_cast(f16x8, wv);
      #pragma unroll
      for (int db=0; db<4; ++db){
        f16x8 vf = *(const f16x8*)(Vc + (32*db + q32)*128 + ((16*hi + 32*ks) ^ swzV));
        ob[db] = __builtin_amdgcn_mfma_f32_32x32x16_f16(vf, pf, ob[db], 0,0,0);
      }
    }
  };

  // rotating V buffer pointers: before body(t), vprev=V[(t-1)%3], vcur=V[t%3],
  // vnext=V[(t+1)%3]
  char* vprev = (char*)V_lds[2];
  char* vcur  = (char*)V_lds[0];
  char* vnext = (char*)V_lds[1];

  // prologue: stage tile 0
  stage_K(Kg, nt0, (char*)K_lds[0], w, l);
  stage_V(Vg, nt0, vcur, w, l);
  __syncthreads();

  // body 0: stage(1); QK^T(0)->stA; (no softmax/PV); barrier
  stage_K(Kg, nt0+1, (char*)K_lds[1], w, l);
  stage_V(Vg, nt0+1, vnext, w, l);
  QKT((const char*)K_lds[0], stA);
  __syncthreads();
  { char* t=vprev; vprev=vcur; vcur=vnext; vnext=t; }

  #pragma unroll 1
  for (int tt=0; tt<15; ++tt){
    const int t1 = 2*tt+1;
    // body t1 (odd): reads K[1], stages K[0]
    stage_K(Kg, nt0+t1+1, (char*)K_lds[0], w, l);
    stage_V(Vg, nt0+t1+1, vnext, w, l);
    QKT((const char*)K_lds[1], stB);
    SMPV(stA, vprev);
    __syncthreads();
    { char* t=vprev; vprev=vcur; vcur=vnext; vnext=t; }
    // body t1+1 (even): reads K[0], stages K[1]
    stage_K(Kg, nt0+t1+2, (char*)K_lds[1], w, l);
    stage_V(Vg, nt0+t1+2, vnext, w, l);
    QKT((const char*)K_lds[0], stA);
    SMPV(stB, vprev);
    __syncthreads();
    { char* t=vprev; vprev=vcur; vcur=vnext; vnext=t; }
  }
  // body 31 (odd, no staging): QK^T(31)->stB; softmax+PV(30)
  QKT((const char*)K_lds[1], stB);
  SMPV(stA, vprev);
  { char* t=vprev; vprev=vcur; vcur=vnext; vnext=t; }
  // epilogue: softmax+PV(31)
  SMPV(stB, vprev);

  // ---- epilogue: O^T[d regs][q=lane&31] -> normalized f16 partials ----
  float l_run = l_loc + __shfl_xor(l_loc, 32);
  float invl = 1.0f / l_run;
  unsigned short* Orow = On + (((size_t)(h*8 + b)*4096) + n0 + wq0 + q32)*128;
  #pragma unroll
  for (int db=0; db<4; ++db)
    #pragma unroll
    for (int g=0; g<4; ++g){
      int2v pk2;
      pk2[0] = __builtin_bit_cast(int, __builtin_amdgcn_cvt_pkrtz(ob[db][4*g+0]*invl, ob[db][4*g+1]*invl));
      pk2[1] = __builtin_bit_cast(int, __builtin_amdgcn_cvt_pkrtz(ob[db][4*g+2]*invl, ob[db][4*g+3]*invl));
      *(int2v*)&Orow[32*db + 8*g + 4*hi] = pk2;
    }
  if (l < 32){
    size_t idx = (size_t)(h*8+b)*4096 + n0 + wq0 + l;
    Mp[idx] = m_run;
    Lp[idx] = l_run;
  }
}

// ---------------- kernel 4: merge halves + out-proj + residual ----
// 1-D grid 1024, b = id&7 (XCD-pinned), 32-row tiles.
__global__ __launch_bounds__(256) void k_merge(
    const unsigned short* __restrict__ On, const float* __restrict__ Mp,
    const float* __restrict__ Lp,
    const unsigned short* __restrict__ Wo, const float* __restrict__ out_b,
    const float* __restrict__ x, float* __restrict__ out)
{
  __shared__ __align__(16) unsigned short y_lds[32*136];
  const int tid = threadIdx.x;
  const int id = blockIdx.x;
  const int b = id & 7, n0 = (id>>3)*32;

  { // phase 1: y = w0*On0 + w1*On1 -> y_lds [n][k] f16
    int row = tid>>3, dq = (tid&7)*16;
    size_t i0 = (size_t)b*4096 + n0 + row;
    size_t i1 = (size_t)(8+b)*4096 + n0 + row;
    float m0 = Mp[i0], m1 = Mp[i1], l0 = Lp[i0], l1 = Lp[i1];
    float M = fmaxf(m0, m1);
    float a0 = fexp2(m0 - M)*l0, a1 = fexp2(m1 - M)*l1;
    float inv = 1.0f/(a0 + a1);
    float w0 = a0*inv, w1 = a1*inv;
    const unsigned short* p0 = On + i0*128 + dq;
    const unsigned short* p1 = On + i1*128 + dq;
    #pragma unroll
    for (int i=0;i<2;++i){
      f16x8 o0 = *(const f16x8*)&p0[8*i];
      f16x8 o1 = *(const f16x8*)&p1[8*i];
      int4v pk;
      #pragma unroll
      for (int j=0;j<4;++j){
        float ya = w0*(float)o0[2*j]   + w1*(float)o1[2*j];
        float yb = w0*(float)o0[2*j+1] + w1*(float)o1[2*j+1];
        pk[j] = __builtin_bit_cast(int, __builtin_amdgcn_cvt_pkrtz(ya, yb));
      }
      *(int4v*)&y_lds[row*136 + dq + 8*i] = pk;
    }
  }
  __syncthreads();

  // phase 2: out = y . Wo^T + out_b + x
  const int w = tid>>6, l = tid&63, l15 = l&15, lhi = l>>4;
  const float* xb = x + (size_t)b*256*4096;
  const f32x4 zero4 = {0.f,0.f,0.f,0.f};
  for (int cb=0; cb<4; ++cb){
    int c0 = 64*w + 16*cb;
    f16x8 aW[4];
    #pragma unroll
    for (int ks=0;ks<4;++ks)
      aW[ks] = *(const f16x8*)&Wo[(size_t)(c0 + l15)*128 + lhi*8 + 32*ks];
    float obv[4];
    #pragma unroll
    for (int r=0;r<4;++r) obv[r] = out_b[c0 + lhi*4 + r];
    #pragma unroll
    for (int nb=0;nb<2;++nb){
      f32x4 acc = zero4;
      #pragma unroll
      for (int ks=0;ks<4;++ks){
        f16x8 yF = *(const f16x8*)&y_lds[(16*nb + l15)*136 + lhi*8 + 32*ks];
        acc = __builtin_amdgcn_mfma_f32_16x16x32_f16(aW[ks], yF, acc, 0,0,0);
      }
      #pragma unroll
      for (int r=0;r<4;++r){
        int c = c0 + lhi*4 + r;
        size_t oi = (size_t)c*4096 + n0 + 16*nb + l15;
        out[(size_t)b*256*4096 + oi] = acc[r] + obv[r] + xb[oi];
      }
    }
  }
}

extern "C" void kernel_launch(void* const* d_in, const int* in_sizes, int n_in,
                              void* d_out, int out_size, void* d_ws, size_t ws_size,
                              hipStream_t stream) {
  (void)in_sizes; (void)n_in; (void)out_size; (void)ws_size;
  const float* x  = (const float*)d_in[0];
  const float* tw = (const float*)d_in[1];
  const float* tb = (const float*)d_in[2];
  const float* pw = (const float*)d_in[3];
  const float* pb = (const float*)d_in[4];
  const float* gw = (const float*)d_in[5];
  const float* gb = (const float*)d_in[6];
  const float* ow = (const float*)d_in[7];
  const float* ob = (const float*)d_in[8];
  float* out = (float*)d_out;

  unsigned short* ws = (unsigned short*)d_ws;
  unsigned short* Wq = ws;                       // 4 x 32768 f16 weights
  unsigned short* Wk = ws + 32768;
  unsigned short* Wg = ws + 65536;
  unsigned short* Wo = ws + 98304;
  unsigned short* Q  = ws + 131072;              // 8*4096*128 f16 each
  unsigned short* Km = Q  + 4194304;
  unsigned short* VT = Km + 4194304;
  unsigned short* On = VT + 4194304;             // 2*8*4096*128 f16
  float* Mp = (float*)(On + 8388608);            // 2*8*4096 f32 (log2 units)
  float* Lp = Mp + 65536;

  hipLaunchKernelGGL(k_wconv, dim3(512), dim3(256), 0, stream, tw, pw, gw, ow, ws);
  hipLaunchKernelGGL(k_proj,  dim3(512), dim3(256), 0, stream,
                     x, Wq, Wk, Wg, tb, pb, gb, Q, Km, VT);
  hipLaunchKernelGGL(k_attn,  dim3(512), dim3(256), 0, stream,
                     Q, Km, VT, On, Mp, Lp);
  hipLaunchKernelGGL(k_merge, dim3(1024), dim3(256), 0, stream,
                     On, Mp, Lp, Wo, ob, x, out);
}